// Round 1
// baseline (1020.008 us; speedup 1.0000x reference)
//
#include <hip/hip_runtime.h>
#include <math.h>

#define NN 4096
#define CC 256

// ---------------------------------------------------------------- gate ----
__global__ __launch_bounds__(256) void gate_kernel(const float* __restrict__ g0,
                                                   float* __restrict__ gate)
{
    int idx = blockIdx.x * 256 + threadIdx.x;      // B*4096 total
    int b  = idx >> 12;
    int hw = idx & 4095;
    int h = hw >> 6, w = hw & 63;
    float ys = h * (31.0f / 63.0f);
    float xs = w * (31.0f / 63.0f);
    int y0 = (int)ys, x0 = (int)xs;                // non-negative -> trunc == floor
    int y1 = min(y0 + 1, 31), x1 = min(x0 + 1, 31);
    float wy = ys - (float)y0, wx = xs - (float)x0;
    const float* g = g0 + b * 1024;
    float g00 = g[y0 * 32 + x0], g01 = g[y0 * 32 + x1];
    float g10 = g[y1 * 32 + x0], g11 = g[y1 * 32 + x1];
    float top = g00 * (1.0f - wx) + g01 * wx;
    float bot = g10 * (1.0f - wx) + g11 * wx;
    float val = top * (1.0f - wy) + bot * wy;
    gate[idx] = 1.0f + 1.0f / (1.0f + __expf(-val));
}

// ---------------------------------------------------------------- qkv -----
// grid: (64, 5).  x: b(2b)|ntile(4b).  y: 0 -> q+k (32+32 outs), 1..4 -> v rows.
__global__ __launch_bounds__(256) void qkv_kernel(
    const float* __restrict__ x,
    const float* __restrict__ Wq, const float* __restrict__ bq,
    const float* __restrict__ Wk, const float* __restrict__ bk,
    const float* __restrict__ Wv, const float* __restrict__ bv,
    const float* __restrict__ gate,
    float* __restrict__ q, float* __restrict__ k, float* __restrict__ vT)
{
    int b = blockIdx.x >> 4;
    int n = (blockIdx.x & 15) * 256 + threadIdx.x;
    int og = blockIdx.y;
    const float* xp = x + (size_t)b * CC * NN + n;
    float g = gate[b * NN + n];

    float acc[64];
#pragma unroll
    for (int i = 0; i < 64; i++) acc[i] = 0.f;

    if (og == 0) {
        for (int c0 = 0; c0 < CC; c0 += 8) {
            float xr[8];
#pragma unroll
            for (int j = 0; j < 8; j++) xr[j] = xp[(size_t)(c0 + j) * NN];
#pragma unroll
            for (int o = 0; o < 32; o++) {
                float aq = acc[o], ak = acc[32 + o];
#pragma unroll
                for (int j = 0; j < 8; j++) {
                    aq = fmaf(Wq[o * CC + c0 + j], xr[j], aq);
                    ak = fmaf(Wk[o * CC + c0 + j], xr[j], ak);
                }
                acc[o] = aq; acc[32 + o] = ak;
            }
        }
#pragma unroll
        for (int o = 0; o < 32; o++) {
            q[((size_t)b * 32 + o) * NN + n] = (acc[o] + bq[o]) * g;
            k[((size_t)b * 32 + o) * NN + n] = (acc[32 + o] + bk[o]) * g;
        }
    } else {
        int ob = (og - 1) * 64;
        for (int c0 = 0; c0 < CC; c0 += 8) {
            float xr[8];
#pragma unroll
            for (int j = 0; j < 8; j++) xr[j] = xp[(size_t)(c0 + j) * NN];
#pragma unroll
            for (int o = 0; o < 64; o++) {
                float a = acc[o];
#pragma unroll
                for (int j = 0; j < 8; j++)
                    a = fmaf(Wv[(ob + o) * CC + c0 + j], xr[j], a);
                acc[o] = a;
            }
        }
        float* vp = vT + ((size_t)b * NN + n) * CC + ob;
#pragma unroll
        for (int o = 0; o < 64; o++) vp[o] = (acc[o] + bv[ob + o]) * g;
    }
}

// ---------------------------------------------------------------- stats ---
// grid: 256 blocks (b*64 m-tiles), 512 threads. BM=64, BN=256 per iter.
__global__ __launch_bounds__(512) void stats_kernel(
    const float* __restrict__ q, const float* __restrict__ k,
    float* __restrict__ rowmax, float* __restrict__ rowsum)
{
    __shared__ float Qs[32][64];
    __shared__ float Ks[32][256];
    __shared__ float redm[64][32];
    __shared__ float reds[64][32];

    int b  = blockIdx.x >> 6;
    int m0 = (blockIdx.x & 63) * 64;
    int tid = threadIdx.x;

    for (int i = tid; i < 32 * 64; i += 512) {
        int d = i >> 6, mm = i & 63;
        Qs[d][mm] = q[((size_t)b * 32 + d) * NN + m0 + mm];
    }

    int mg = (tid & 15) * 4;       // 4 consecutive m
    int ng = (tid >> 4) * 8;       // 8 consecutive n (32 groups)
    float rmax[4], rsum[4];
#pragma unroll
    for (int i = 0; i < 4; i++) { rmax[i] = -1e30f; rsum[i] = 0.f; }

    for (int nt = 0; nt < 16; nt++) {
        int n0 = nt * 256;
        __syncthreads();
        for (int i = tid; i < 32 * 256; i += 512) {
            int d = i >> 8, nn = i & 255;
            Ks[d][nn] = k[((size_t)b * 32 + d) * NN + n0 + nn];
        }
        __syncthreads();

        float s[4][8];
#pragma unroll
        for (int i = 0; i < 4; i++)
#pragma unroll
            for (int j = 0; j < 8; j++) s[i][j] = 0.f;

#pragma unroll
        for (int d = 0; d < 32; d++) {
            float4 qv = *(const float4*)&Qs[d][mg];
            float4 ka = *(const float4*)&Ks[d][ng];
            float4 kb = *(const float4*)&Ks[d][ng + 4];
            float qq[4] = {qv.x, qv.y, qv.z, qv.w};
            float kk[8] = {ka.x, ka.y, ka.z, ka.w, kb.x, kb.y, kb.z, kb.w};
#pragma unroll
            for (int i = 0; i < 4; i++)
#pragma unroll
                for (int j = 0; j < 8; j++)
                    s[i][j] = fmaf(qq[i], kk[j], s[i][j]);
        }

#pragma unroll
        for (int i = 0; i < 4; i++) {
            float tm = s[i][0];
#pragma unroll
            for (int j = 1; j < 8; j++) tm = fmaxf(tm, s[i][j]);
            float nm = fmaxf(rmax[i], tm);
            float add = 0.f;
#pragma unroll
            for (int j = 0; j < 8; j++) add += __expf(s[i][j] - nm);
            rsum[i] = rsum[i] * __expf(rmax[i] - nm) + add;
            rmax[i] = nm;
        }
    }

#pragma unroll
    for (int i = 0; i < 4; i++) {
        redm[mg + i][tid >> 4] = rmax[i];
        reds[mg + i][tid >> 4] = rsum[i];
    }
    __syncthreads();
    if (tid < 64) {
        float M = -1e30f;
        for (int g2 = 0; g2 < 32; g2++) M = fmaxf(M, redm[tid][g2]);
        float S = 0.f;
        for (int g2 = 0; g2 < 32; g2++) S += reds[tid][g2] * __expf(redm[tid][g2] - M);
        rowmax[b * NN + m0 + tid] = M;
        rowsum[b * NN + m0 + tid] = S;
    }
}

// ---------------------------------------------------------------- out -----
// grid: 256 blocks (b*64 m-tiles), 512 threads. BM=64, n-tile 64.
__global__ __launch_bounds__(512) void out_kernel(
    const float* __restrict__ q, const float* __restrict__ k,
    const float* __restrict__ vT, const float* __restrict__ rowmax,
    const float* __restrict__ rowsum, const float* __restrict__ x,
    const float* __restrict__ gamma, float* __restrict__ out)
{
    __shared__ float Qs[32][64];
    __shared__ float Ks[32][64];
    __shared__ float P[64][64];     // P[n_in_tile][m]
    __shared__ float maxs[64];
    __shared__ float isum[64];

    int b  = blockIdx.x >> 6;
    int m0 = (blockIdx.x & 63) * 64;
    int tid = threadIdx.x;

    for (int i = tid; i < 32 * 64; i += 512) {
        int d = i >> 6, mm = i & 63;
        Qs[d][mm] = q[((size_t)b * 32 + d) * NN + m0 + mm];
    }
    if (tid < 64) {
        maxs[tid] = rowmax[b * NN + m0 + tid];
        isum[tid] = 1.0f / rowsum[b * NN + m0 + tid];
    }

    int mg  = (tid & 15) * 4;      // energy: 4 m
    int ng2 = (tid >> 4) * 2;      // energy: 2 n
    int cg  = (tid & 63) * 4;      // pv: 4 channels
    int mb  = (tid >> 6) * 8;      // pv: 8 m

    float O[4][8];
#pragma unroll
    for (int u = 0; u < 4; u++)
#pragma unroll
        for (int i = 0; i < 8; i++) O[u][i] = 0.f;

    for (int nt = 0; nt < 64; nt++) {
        int n0 = nt * 64;
        __syncthreads();
        for (int i = tid; i < 32 * 64; i += 512) {
            int d = i >> 6, nn = i & 63;
            Ks[d][nn] = k[((size_t)b * 32 + d) * NN + n0 + nn];
        }
        __syncthreads();

        float s[4][2];
#pragma unroll
        for (int i = 0; i < 4; i++) { s[i][0] = 0.f; s[i][1] = 0.f; }
#pragma unroll
        for (int d = 0; d < 32; d++) {
            float4 qv = *(const float4*)&Qs[d][mg];
            float k0 = Ks[d][ng2];
            float k1 = Ks[d][ng2 + 1];
            s[0][0] = fmaf(qv.x, k0, s[0][0]); s[0][1] = fmaf(qv.x, k1, s[0][1]);
            s[1][0] = fmaf(qv.y, k0, s[1][0]); s[1][1] = fmaf(qv.y, k1, s[1][1]);
            s[2][0] = fmaf(qv.z, k0, s[2][0]); s[2][1] = fmaf(qv.z, k1, s[2][1]);
            s[3][0] = fmaf(qv.w, k0, s[3][0]); s[3][1] = fmaf(qv.w, k1, s[3][1]);
        }
#pragma unroll
        for (int j = 0; j < 2; j++) {
            float4 pv;
            pv.x = __expf(s[0][j] - maxs[mg + 0]) * isum[mg + 0];
            pv.y = __expf(s[1][j] - maxs[mg + 1]) * isum[mg + 1];
            pv.z = __expf(s[2][j] - maxs[mg + 2]) * isum[mg + 2];
            pv.w = __expf(s[3][j] - maxs[mg + 3]) * isum[mg + 3];
            *(float4*)&P[ng2 + j][mg] = pv;
        }
        __syncthreads();

        const float* vp = vT + ((size_t)b * NN + n0) * CC + cg;
#pragma unroll 8
        for (int j = 0; j < 64; j++) {
            float4 vv = *(const float4*)(vp + (size_t)j * CC);
            float4 pa = *(const float4*)&P[j][mb];
            float4 pb = *(const float4*)&P[j][mb + 4];
            float vl[4] = {vv.x, vv.y, vv.z, vv.w};
            float pp[8] = {pa.x, pa.y, pa.z, pa.w, pb.x, pb.y, pb.z, pb.w};
#pragma unroll
            for (int u = 0; u < 4; u++)
#pragma unroll
                for (int i = 0; i < 8; i++)
                    O[u][i] = fmaf(vl[u], pp[i], O[u][i]);
        }
    }

    float gm = gamma[0];
#pragma unroll
    for (int u = 0; u < 4; u++) {
        const float* xp = x + ((size_t)b * CC + cg + u) * NN + m0 + mb;
        float* op = out + ((size_t)b * CC + cg + u) * NN + m0 + mb;
        float4 xa = *(const float4*)xp;
        float4 xb = *(const float4*)(xp + 4);
        float4 ra, rb;
        ra.x = fmaf(gm, O[u][0], xa.x);
        ra.y = fmaf(gm, O[u][1], xa.y);
        ra.z = fmaf(gm, O[u][2], xa.z);
        ra.w = fmaf(gm, O[u][3], xa.w);
        rb.x = fmaf(gm, O[u][4], xb.x);
        rb.y = fmaf(gm, O[u][5], xb.y);
        rb.z = fmaf(gm, O[u][6], xb.z);
        rb.w = fmaf(gm, O[u][7], xb.w);
        *(float4*)op = ra;
        *(float4*)(op + 4) = rb;
    }
}

// ---------------------------------------------------------------- launch --
extern "C" void kernel_launch(void* const* d_in, const int* in_sizes, int n_in,
                              void* d_out, int out_size, void* d_ws, size_t ws_size,
                              hipStream_t stream)
{
    const float* x     = (const float*)d_in[0];
    const float* g0    = (const float*)d_in[1];
    const float* Wq    = (const float*)d_in[2];
    const float* bq    = (const float*)d_in[3];
    const float* Wk    = (const float*)d_in[4];
    const float* bk    = (const float*)d_in[5];
    const float* Wv    = (const float*)d_in[6];
    const float* bv    = (const float*)d_in[7];
    const float* gamma = (const float*)d_in[8];
    float* out = (float*)d_out;

    // workspace layout (floats): ~21.2 MB total
    float* ws   = (float*)d_ws;
    float* q    = ws;                                  // 4*32*4096
    float* kk   = q  + (size_t)4 * 32 * NN;            // 4*32*4096
    float* vT   = kk + (size_t)4 * 32 * NN;            // 4*4096*256
    float* gate = vT + (size_t)4 * NN * CC;            // 4*4096
    float* rmax = gate + (size_t)4 * NN;               // 4*4096
    float* rsum = rmax + (size_t)4 * NN;               // 4*4096

    hipLaunchKernelGGL(gate_kernel, dim3(64), dim3(256), 0, stream, g0, gate);
    hipLaunchKernelGGL(qkv_kernel, dim3(64, 5), dim3(256), 0, stream,
                       x, Wq, bq, Wk, bk, Wv, bv, gate, q, kk, vT);
    hipLaunchKernelGGL(stats_kernel, dim3(256), dim3(512), 0, stream, q, kk, rmax, rsum);
    hipLaunchKernelGGL(out_kernel, dim3(256), dim3(512), 0, stream,
                       q, kk, vT, rmax, rsum, x, gamma, out);
}

// Round 2
// 547.251 us; speedup vs baseline: 1.8639x; 1.8639x over previous
//
#include <hip/hip_runtime.h>
#include <math.h>

#define NN 4096
#define CC 256

typedef unsigned short u16;
typedef float f32x4 __attribute__((ext_vector_type(4)));
typedef float f32x16 __attribute__((ext_vector_type(16)));
typedef short s16x8 __attribute__((ext_vector_type(8)));

#define ZERO16 {0.f,0.f,0.f,0.f,0.f,0.f,0.f,0.f,0.f,0.f,0.f,0.f,0.f,0.f,0.f,0.f}

__device__ __forceinline__ u16 f2bf(float f){
    unsigned u = __float_as_uint(f);
    return (u16)((u + 0x7fffu + ((u >> 16) & 1u)) >> 16);
}
__device__ __forceinline__ float bf2f(u16 h){
    return __uint_as_float(((unsigned)h) << 16);
}

// ---------------------------------------------------------------- gate ----
__global__ __launch_bounds__(256) void gate_kernel(const float* __restrict__ g0,
                                                   float* __restrict__ gate)
{
    int idx = blockIdx.x * 256 + threadIdx.x;      // B*4096 total
    int b  = idx >> 12;
    int hw = idx & 4095;
    int h = hw >> 6, w = hw & 63;
    float ys = h * (31.0f / 63.0f);
    float xs = w * (31.0f / 63.0f);
    int y0 = (int)ys, x0 = (int)xs;
    int y1 = min(y0 + 1, 31), x1 = min(x0 + 1, 31);
    float wy = ys - (float)y0, wx = xs - (float)x0;
    const float* g = g0 + b * 1024;
    float g00 = g[y0 * 32 + x0], g01 = g[y0 * 32 + x1];
    float g10 = g[y1 * 32 + x0], g11 = g[y1 * 32 + x1];
    float top = g00 * (1.0f - wx) + g01 * wx;
    float bot = g10 * (1.0f - wx) + g11 * wx;
    float val = top * (1.0f - wy) + bot * wy;
    gate[idx] = 1.0f + 1.0f / (1.0f + __expf(-val));
}

// ---------------------------------------------------------------- qkv -----
// grid (64, 5): y==0 -> q+k (hi/lo bf16 splits, fragment layout [B][N][32]);
// y=1..4 -> v rows -> bf16 [B][C][N].
__global__ __launch_bounds__(256) void qkv_kernel(
    const float* __restrict__ x,
    const float* __restrict__ Wq, const float* __restrict__ bq,
    const float* __restrict__ Wk, const float* __restrict__ bk,
    const float* __restrict__ Wv, const float* __restrict__ bv,
    const float* __restrict__ gate,
    u16* __restrict__ qhi, u16* __restrict__ qlo,
    u16* __restrict__ khi, u16* __restrict__ klo,
    u16* __restrict__ vbf)
{
    int b = blockIdx.x >> 4;
    int n = (blockIdx.x & 15) * 256 + threadIdx.x;
    int og = blockIdx.y;
    const float* xp = x + (size_t)b * CC * NN + n;
    float g = gate[b * NN + n];

    float acc[64];
#pragma unroll
    for (int i = 0; i < 64; i++) acc[i] = 0.f;

    if (og == 0) {
        for (int c0 = 0; c0 < CC; c0 += 8) {
            float xr[8];
#pragma unroll
            for (int j = 0; j < 8; j++) xr[j] = xp[(size_t)(c0 + j) * NN];
#pragma unroll
            for (int o = 0; o < 32; o++) {
                float aq = acc[o], ak = acc[32 + o];
#pragma unroll
                for (int j = 0; j < 8; j++) {
                    aq = fmaf(Wq[o * CC + c0 + j], xr[j], aq);
                    ak = fmaf(Wk[o * CC + c0 + j], xr[j], ak);
                }
                acc[o] = aq; acc[32 + o] = ak;
            }
        }
        size_t qb = ((size_t)b * NN + n) * 32;
#pragma unroll
        for (int o = 0; o < 32; o += 2) {
            float q0 = (acc[o] + bq[o]) * g;
            float q1 = (acc[o + 1] + bq[o + 1]) * g;
            u16 qh0 = f2bf(q0), qh1 = f2bf(q1);
            u16 ql0 = f2bf(q0 - bf2f(qh0)), ql1 = f2bf(q1 - bf2f(qh1));
            *(unsigned*)(qhi + qb + o) = (unsigned)qh0 | ((unsigned)qh1 << 16);
            *(unsigned*)(qlo + qb + o) = (unsigned)ql0 | ((unsigned)ql1 << 16);
            float k0 = (acc[32 + o] + bk[o]) * g;
            float k1 = (acc[33 + o] + bk[o + 1]) * g;
            u16 kh0 = f2bf(k0), kh1 = f2bf(k1);
            u16 kl0 = f2bf(k0 - bf2f(kh0)), kl1 = f2bf(k1 - bf2f(kh1));
            *(unsigned*)(khi + qb + o) = (unsigned)kh0 | ((unsigned)kh1 << 16);
            *(unsigned*)(klo + qb + o) = (unsigned)kl0 | ((unsigned)kl1 << 16);
        }
    } else {
        int ob = (og - 1) * 64;
        for (int c0 = 0; c0 < CC; c0 += 8) {
            float xr[8];
#pragma unroll
            for (int j = 0; j < 8; j++) xr[j] = xp[(size_t)(c0 + j) * NN];
#pragma unroll
            for (int o = 0; o < 64; o++) {
                float a = acc[o];
#pragma unroll
                for (int j = 0; j < 8; j++)
                    a = fmaf(Wv[(ob + o) * CC + c0 + j], xr[j], a);
                acc[o] = a;
            }
        }
#pragma unroll
        for (int o = 0; o < 64; o++)
            vbf[((size_t)b * CC + ob + o) * NN + n] = f2bf((acc[o] + bv[ob + o]) * g);
    }
}

// ---------------------------------------------------------------- stats ---
// 256 blocks x 4 waves. Wave = (strip = w&1 of 2x32m, nhalf = w>>1).
// Split-bf16 energy via 32x32x16 MFMA; online max/sum; lse = max + log(sum).
__global__ __launch_bounds__(256) void stats_kernel(
    const u16* __restrict__ qhi, const u16* __restrict__ qlo,
    const u16* __restrict__ khi, const u16* __restrict__ klo,
    float* __restrict__ lse)
{
    __shared__ float Sm[4][2][16], Ss[4][2][16];
    int bid = blockIdx.x;
    int b = (bid >> 1) & 3;                       // XCD-clustered batches
    int mtile = (bid >> 3) + 32 * (bid & 1);
    int w = threadIdx.x >> 6, l = threadIdx.x & 63;
    int l5 = l >> 5, l31 = l & 31;
    int mS = mtile * 64 + 32 * (w & 1);
    int nh = w >> 1;

    size_t qo = ((size_t)b * NN + mS + l31) * 32 + 8 * l5;
    s16x8 qh0 = *(const s16x8*)(qhi + qo), ql0 = *(const s16x8*)(qlo + qo);
    s16x8 qh1 = *(const s16x8*)(qhi + qo + 16), ql1 = *(const s16x8*)(qlo + qo + 16);

    float rmax[16], rsum[16];
#pragma unroll
    for (int r = 0; r < 16; r++) { rmax[r] = -1e30f; rsum[r] = 0.f; }

    for (int n0 = nh * 2048; n0 < nh * 2048 + 2048; n0 += 64) {
        f32x16 S[2];
#pragma unroll
        for (int s = 0; s < 2; s++) {
            size_t ko = ((size_t)b * NN + n0 + 32 * s + l31) * 32 + 8 * l5;
            s16x8 kh0 = *(const s16x8*)(khi + ko), kl0 = *(const s16x8*)(klo + ko);
            s16x8 kh1 = *(const s16x8*)(khi + ko + 16), kl1 = *(const s16x8*)(klo + ko + 16);
            f32x16 a = ZERO16;
            a = __builtin_amdgcn_mfma_f32_32x32x16_bf16(ql0, kh0, a, 0, 0, 0);
            a = __builtin_amdgcn_mfma_f32_32x32x16_bf16(qh0, kl0, a, 0, 0, 0);
            a = __builtin_amdgcn_mfma_f32_32x32x16_bf16(qh0, kh0, a, 0, 0, 0);
            a = __builtin_amdgcn_mfma_f32_32x32x16_bf16(ql1, kh1, a, 0, 0, 0);
            a = __builtin_amdgcn_mfma_f32_32x32x16_bf16(qh1, kl1, a, 0, 0, 0);
            a = __builtin_amdgcn_mfma_f32_32x32x16_bf16(qh1, kh1, a, 0, 0, 0);
            S[s] = a;
        }
#pragma unroll
        for (int r = 0; r < 16; r++) {
            float v0 = S[0][r], v1 = S[1][r];
            float nm = fmaxf(rmax[r], fmaxf(v0, v1));
            rsum[r] = rsum[r] * __expf(rmax[r] - nm) + __expf(v0 - nm) + __expf(v1 - nm);
            rmax[r] = nm;
        }
    }

    // butterfly over the 32 lanes sharing each row set
#pragma unroll
    for (int r = 0; r < 16; r++) {
#pragma unroll
        for (int off = 16; off >= 1; off >>= 1) {
            float om = __shfl_xor(rmax[r], off);
            float os = __shfl_xor(rsum[r], off);
            float nm = fmaxf(rmax[r], om);
            rsum[r] = rsum[r] * __expf(rmax[r] - nm) + os * __expf(om - nm);
            rmax[r] = nm;
        }
    }

    if (l31 == 0) {
#pragma unroll
        for (int r = 0; r < 16; r++) { Sm[w][l5][r] = rmax[r]; Ss[w][l5][r] = rsum[r]; }
    }
    __syncthreads();
    if (w < 2 && l31 == 0) {
#pragma unroll
        for (int r = 0; r < 16; r++) {
            float m1 = Sm[w][l5][r], m2 = Sm[w + 2][l5][r];
            float nm = fmaxf(m1, m2);
            float s = Ss[w][l5][r] * __expf(m1 - nm) + Ss[w + 2][l5][r] * __expf(m2 - nm);
            int m = mS + (r & 3) + 8 * (r >> 2) + 4 * l5;
            lse[b * NN + m] = nm + __logf(s);
        }
    }
}

// ---------------------------------------------------------------- out -----
// 256 blocks x 4 independent waves (no barriers). Wave = (strip = w&1,
// c-half = w>>1, 128 channels). Energy recomputed (split bf16), P staged in
// per-wave swizzled LDS tile, PV = 32x32x16 MFMA vs bf16 V.
__global__ __launch_bounds__(256) void out_kernel(
    const u16* __restrict__ qhi, const u16* __restrict__ qlo,
    const u16* __restrict__ khi, const u16* __restrict__ klo,
    const u16* __restrict__ vbf, const float* __restrict__ lse,
    const float* __restrict__ x, const float* __restrict__ gamma,
    float* __restrict__ out)
{
    __shared__ u16 Pb[4][2048];                   // 4 KB per wave, swizzled
    int bid = blockIdx.x;
    int b = (bid >> 1) & 3;
    int mtile = (bid >> 3) + 32 * (bid & 1);
    int w = threadIdx.x >> 6, l = threadIdx.x & 63;
    int l5 = l >> 5, l31 = l & 31;
    int mS = mtile * 64 + 32 * (w & 1);
    int ch = (w >> 1) * 128;

    size_t qo = ((size_t)b * NN + mS + l31) * 32 + 8 * l5;
    s16x8 qh0 = *(const s16x8*)(qhi + qo), ql0 = *(const s16x8*)(qlo + qo);
    s16x8 qh1 = *(const s16x8*)(qhi + qo + 16), ql1 = *(const s16x8*)(qlo + qo + 16);

    float lr[16];
#pragma unroll
    for (int r = 0; r < 16; r++)
        lr[r] = lse[b * NN + mS + (r & 3) + 8 * (r >> 2) + 4 * l5];

    f32x16 acc[4] = {ZERO16, ZERO16, ZERO16, ZERO16};
    u16* Pw = &Pb[w][0];

    for (int n0 = 0; n0 < NN; n0 += 64) {
        f32x16 S[2];
#pragma unroll
        for (int s = 0; s < 2; s++) {
            size_t ko = ((size_t)b * NN + n0 + 32 * s + l31) * 32 + 8 * l5;
            s16x8 kh0 = *(const s16x8*)(khi + ko), kl0 = *(const s16x8*)(klo + ko);
            s16x8 kh1 = *(const s16x8*)(khi + ko + 16), kl1 = *(const s16x8*)(klo + ko + 16);
            f32x16 a = ZERO16;
            a = __builtin_amdgcn_mfma_f32_32x32x16_bf16(ql0, kh0, a, 0, 0, 0);
            a = __builtin_amdgcn_mfma_f32_32x32x16_bf16(qh0, kl0, a, 0, 0, 0);
            a = __builtin_amdgcn_mfma_f32_32x32x16_bf16(qh0, kh0, a, 0, 0, 0);
            a = __builtin_amdgcn_mfma_f32_32x32x16_bf16(ql1, kh1, a, 0, 0, 0);
            a = __builtin_amdgcn_mfma_f32_32x32x16_bf16(qh1, kl1, a, 0, 0, 0);
            a = __builtin_amdgcn_mfma_f32_32x32x16_bf16(qh1, kh1, a, 0, 0, 0);
            S[s] = a;
        }
        // P = exp(S - lse)  ->  bf16  ->  swizzled LDS (write D-layout)
#pragma unroll
        for (int s = 0; s < 2; s++) {
#pragma unroll
            for (int r = 0; r < 16; r++) {
                float p = __expf(S[s][r] - lr[r]);
                int mw = (r & 3) + 8 * (r >> 2) + 4 * l5;
                int off = (mw * 128 + (l31 + 32 * s) * 2) ^ ((mw & 7) << 4);
                *(u16*)((char*)Pw + off) = f2bf(p);
            }
        }
        asm volatile("s_waitcnt lgkmcnt(0)" ::: "memory");
        // PV: A = P (read A-layout from LDS), B = v[n][c] from [C][N] global
#pragma unroll
        for (int ks = 0; ks < 4; ks++) {
            int ro = (l31 * 128 + ks * 32 + l5 * 16) ^ ((l31 & 7) << 4);
            s16x8 pa = *(const s16x8*)((const char*)Pw + ro);
            const u16* vp = vbf + ((size_t)b * CC + ch + l31) * NN + n0 + ks * 16 + 8 * l5;
#pragma unroll
            for (int cs = 0; cs < 4; cs++) {
                s16x8 vv = *(const s16x8*)(vp + (size_t)cs * 32 * NN);
                acc[cs] = __builtin_amdgcn_mfma_f32_32x32x16_bf16(pa, vv, acc[cs], 0, 0, 0);
            }
        }
    }

    float gm = gamma[0];
#pragma unroll
    for (int cs = 0; cs < 4; cs++) {
        int c = ch + cs * 32 + l31;
#pragma unroll
        for (int t = 0; t < 4; t++) {
            size_t o = ((size_t)b * CC + c) * NN + mS + 8 * t + 4 * l5;
            float4 x4 = *(const float4*)(x + o);
            float4 r4;
            r4.x = fmaf(gm, acc[cs][4 * t + 0], x4.x);
            r4.y = fmaf(gm, acc[cs][4 * t + 1], x4.y);
            r4.z = fmaf(gm, acc[cs][4 * t + 2], x4.z);
            r4.w = fmaf(gm, acc[cs][4 * t + 3], x4.w);
            *(float4*)(out + o) = r4;
        }
    }
}

// ---------------------------------------------------------------- launch --
extern "C" void kernel_launch(void* const* d_in, const int* in_sizes, int n_in,
                              void* d_out, int out_size, void* d_ws, size_t ws_size,
                              hipStream_t stream)
{
    const float* x     = (const float*)d_in[0];
    const float* g0    = (const float*)d_in[1];
    const float* Wq    = (const float*)d_in[2];
    const float* bq    = (const float*)d_in[3];
    const float* Wk    = (const float*)d_in[4];
    const float* bk    = (const float*)d_in[5];
    const float* Wv    = (const float*)d_in[6];
    const float* bv    = (const float*)d_in[7];
    const float* gamma = (const float*)d_in[8];
    float* out = (float*)d_out;

    char* p = (char*)d_ws;
    u16* qhi = (u16*)p; p += (size_t)4 * NN * 32 * 2;   // 1 MB each
    u16* qlo = (u16*)p; p += (size_t)4 * NN * 32 * 2;
    u16* khi = (u16*)p; p += (size_t)4 * NN * 32 * 2;
    u16* klo = (u16*)p; p += (size_t)4 * NN * 32 * 2;
    u16* vbf = (u16*)p; p += (size_t)4 * CC * NN * 2;   // 8 MB
    float* gate = (float*)p; p += (size_t)4 * NN * 4;
    float* lse  = (float*)p; p += (size_t)4 * NN * 4;

    hipLaunchKernelGGL(gate_kernel, dim3(64), dim3(256), 0, stream, g0, gate);
    hipLaunchKernelGGL(qkv_kernel, dim3(64, 5), dim3(256), 0, stream,
                       x, Wq, bq, Wk, bk, Wv, bv, gate, qhi, qlo, khi, klo, vbf);
    hipLaunchKernelGGL(stats_kernel, dim3(256), dim3(256), 0, stream,
                       qhi, qlo, khi, klo, lse);
    hipLaunchKernelGGL(out_kernel, dim3(256), dim3(256), 0, stream,
                       qhi, qlo, khi, klo, vbf, lse, x, gamma, out);
}

// Round 3
// 185.451 us; speedup vs baseline: 5.5001x; 2.9509x over previous
//
#include <hip/hip_runtime.h>
#include <math.h>

#define NN 4096
#define CC 256

typedef unsigned short u16;
typedef float f32x16 __attribute__((ext_vector_type(16)));
typedef short s16x8 __attribute__((ext_vector_type(8)));

#define ZERO16 {0.f,0.f,0.f,0.f,0.f,0.f,0.f,0.f,0.f,0.f,0.f,0.f,0.f,0.f,0.f,0.f}

__device__ __forceinline__ u16 f2bf(float f){
    unsigned u = __float_as_uint(f);
    return (u16)((u + 0x7fffu + ((u >> 16) & 1u)) >> 16);
}
__device__ __forceinline__ float bf2f(u16 h){
    return __uint_as_float(((unsigned)h) << 16);
}
__device__ __forceinline__ void split8(const float* f, s16x8& hi, s16x8& lo){
#pragma unroll
    for (int j = 0; j < 8; j++) {
        u16 h = f2bf(f[j]);
        hi[j] = (short)h;
        lo[j] = (short)f2bf(f[j] - bf2f(h));
    }
}

// ---------------------------------------------------------------- gate ----
__global__ __launch_bounds__(256) void gate_kernel(const float* __restrict__ g0,
                                                   float* __restrict__ gate)
{
    int idx = blockIdx.x * 256 + threadIdx.x;
    int b  = idx >> 12;
    int hw = idx & 4095;
    int h = hw >> 6, w = hw & 63;
    float ys = h * (31.0f / 63.0f);
    float xs = w * (31.0f / 63.0f);
    int y0 = (int)ys, x0 = (int)xs;
    int y1 = min(y0 + 1, 31), x1 = min(x0 + 1, 31);
    float wy = ys - (float)y0, wx = xs - (float)x0;
    const float* g = g0 + b * 1024;
    float g00 = g[y0 * 32 + x0], g01 = g[y0 * 32 + x1];
    float g10 = g[y1 * 32 + x0], g11 = g[y1 * 32 + x1];
    float top = g00 * (1.0f - wx) + g01 * wx;
    float bot = g10 * (1.0f - wx) + g11 * wx;
    float val = top * (1.0f - wy) + bot * wy;
    gate[idx] = 1.0f + 1.0f / (1.0f + __expf(-val));
}

// ---------------------------------------------------------------- qkv -----
// 512 blocks: vflag=bid&1, b=(bid>>1)&3, nt=bid>>3 (64 n-tiles of 64).
// qk path: hi/lo split MFMA (fp32-accurate); v path: plain bf16 MFMA.
__global__ __launch_bounds__(256) void qkv_kernel(
    const float* __restrict__ x,
    const float* __restrict__ Wq, const float* __restrict__ bq,
    const float* __restrict__ Wk, const float* __restrict__ bk,
    const float* __restrict__ Wv, const float* __restrict__ bv,
    const float* __restrict__ gate,
    u16* __restrict__ qhi, u16* __restrict__ qlo,
    u16* __restrict__ khi, u16* __restrict__ klo,
    u16* __restrict__ vbf)
{
    int bid = blockIdx.x;
    int vflag = bid & 1;
    int b  = (bid >> 1) & 3;
    int nt = bid >> 3;
    int n0 = nt * 64;
    int w = threadIdx.x >> 6, l = threadIdx.x & 63;
    int l5 = l >> 5, l31 = l & 31;

    if (!vflag) {
        // ---- q,k: 64 outs x 64 n. wave: osub=w&1 (0=q,1=k), ns=w>>1.
        int osub = w & 1, ns = w >> 1;
        const float* W    = osub ? Wk : Wq;
        const float* bias = osub ? bk : bq;
        u16* dhi = osub ? khi : qhi;
        u16* dlo = osub ? klo : qlo;
        int n = n0 + ns * 32 + l31;

        f32x16 acc = ZERO16;
        for (int ks = 0; ks < 16; ks++) {
            int c0 = ks * 16 + 8 * l5;
            const float* wrow = W + l31 * CC + c0;
            float wf[8];
            *(float4*)&wf[0] = *(const float4*)wrow;
            *(float4*)&wf[4] = *(const float4*)(wrow + 4);
            s16x8 whi, wlo; split8(wf, whi, wlo);
            float xf[8];
#pragma unroll
            for (int j = 0; j < 8; j++)
                xf[j] = x[(size_t)(b * CC + c0 + j) * NN + n];
            s16x8 xhi, xlo; split8(xf, xhi, xlo);
            acc = __builtin_amdgcn_mfma_f32_32x32x16_bf16(whi, xhi, acc, 0, 0, 0);
            acc = __builtin_amdgcn_mfma_f32_32x32x16_bf16(whi, xlo, acc, 0, 0, 0);
            acc = __builtin_amdgcn_mfma_f32_32x32x16_bf16(wlo, xhi, acc, 0, 0, 0);
        }
        float g = gate[b * NN + n];
        size_t rowo = ((size_t)b * NN + n) * 32;
#pragma unroll
        for (int t = 0; t < 4; t++) {
            int ob = 8 * t + 4 * l5;
            unsigned h01 = 0, h23 = 0, l01 = 0, l23 = 0;
#pragma unroll
            for (int j = 0; j < 4; j++) {
                float v = (acc[4 * t + j] + bias[ob + j]) * g;
                u16 h = f2bf(v);
                u16 lo = f2bf(v - bf2f(h));
                if (j < 2) { h01 |= ((unsigned)h) << (16 * j); l01 |= ((unsigned)lo) << (16 * j); }
                else       { h23 |= ((unsigned)h) << (16 * (j - 2)); l23 |= ((unsigned)lo) << (16 * (j - 2)); }
            }
            *(unsigned*)(dhi + rowo + ob)     = h01;
            *(unsigned*)(dhi + rowo + ob + 2) = h23;
            *(unsigned*)(dlo + rowo + ob)     = l01;
            *(unsigned*)(dlo + rowo + ob + 2) = l23;
        }
    } else {
        // ---- v: 256 outs x 64 n. wave: ns=w&1, oh=w>>1 (4 osubs each).
        int ns = w & 1, oh = w >> 1;
        int n = n0 + ns * 32 + l31;

        f32x16 acc[4] = {ZERO16, ZERO16, ZERO16, ZERO16};
        for (int ks = 0; ks < 16; ks++) {
            int c0 = ks * 16 + 8 * l5;
            float xf[8];
#pragma unroll
            for (int j = 0; j < 8; j++)
                xf[j] = x[(size_t)(b * CC + c0 + j) * NN + n];
            s16x8 xhi;
#pragma unroll
            for (int j = 0; j < 8; j++) xhi[j] = (short)f2bf(xf[j]);
#pragma unroll
            for (int i = 0; i < 4; i++) {
                const float* wrow = Wv + (size_t)((oh * 4 + i) * 32 + l31) * CC + c0;
                float wf[8];
                *(float4*)&wf[0] = *(const float4*)wrow;
                *(float4*)&wf[4] = *(const float4*)(wrow + 4);
                s16x8 whi;
#pragma unroll
                for (int j = 0; j < 8; j++) whi[j] = (short)f2bf(wf[j]);
                acc[i] = __builtin_amdgcn_mfma_f32_32x32x16_bf16(whi, xhi, acc[i], 0, 0, 0);
            }
        }
        float g = gate[b * NN + n];
#pragma unroll
        for (int i = 0; i < 4; i++) {
            int cb = (oh * 4 + i) * 32;
#pragma unroll
            for (int r = 0; r < 16; r++) {
                int c = cb + (r & 3) + 8 * (r >> 2) + 4 * l5;
                vbf[((size_t)b * CC + c) * NN + n] = f2bf((acc[i][r] + bv[c]) * g);
            }
        }
    }
}

// ---------------------------------------------------------------- stats ---
// 256 blocks x 8 waves. Waves: strip=w&1 (32 m), ns=w>>1 (32 n of 128-tile).
// K staged in swizzled LDS; online max/sum; lse out.
__global__ __launch_bounds__(512) void stats_kernel(
    const u16* __restrict__ qhi, const u16* __restrict__ qlo,
    const u16* __restrict__ khi, const u16* __restrict__ klo,
    float* __restrict__ lse)
{
    __shared__ u16 Klds[128 * 64];          // [n][hi32|lo32], 128 B rows
    __shared__ float Sm[8][2][16], Ss[8][2][16];
    int bid = blockIdx.x;
    int b  = (bid >> 1) & 3;
    int mt = (bid >> 3) | ((bid & 1) << 5);
    int tid = threadIdx.x;
    int w = tid >> 6, l = tid & 63;
    int l5 = l >> 5, l31 = l & 31;
    int strip = w & 1, ns = w >> 1;
    int mS = mt * 64 + strip * 32;

    size_t qo = ((size_t)b * NN + mS + l31) * 32 + 8 * l5;
    s16x8 qh0 = *(const s16x8*)(qhi + qo), ql0 = *(const s16x8*)(qlo + qo);
    s16x8 qh1 = *(const s16x8*)(qhi + qo + 16), ql1 = *(const s16x8*)(qlo + qo + 16);

    float rmax[16], rsum[16];
#pragma unroll
    for (int r = 0; r < 16; r++) { rmax[r] = -1e30f; rsum[r] = 0.f; }

    int sn = tid >> 2, sq = tid & 3;       // staging: n-row, 16B chunk
    char* KL = (char*)Klds;
    int nn = ns * 32 + l31;
    int rb = nn * 128, sw = (nn & 7) << 4;

    for (int it = 0; it < 32; it++) {
        int n0 = it * 128;
        int swz = (sn & 7) << 4;
        *(s16x8*)(KL + sn * 128 + ((sq * 16) ^ swz)) =
            *(const s16x8*)((const char*)(khi + ((size_t)b * NN + n0 + sn) * 32) + sq * 16);
        *(s16x8*)(KL + sn * 128 + ((64 + sq * 16) ^ swz)) =
            *(const s16x8*)((const char*)(klo + ((size_t)b * NN + n0 + sn) * 32) + sq * 16);
        __syncthreads();

        s16x8 kh0 = *(const s16x8*)(KL + rb + ((16 * l5) ^ sw));
        s16x8 kh1 = *(const s16x8*)(KL + rb + ((32 + 16 * l5) ^ sw));
        s16x8 kl0 = *(const s16x8*)(KL + rb + ((64 + 16 * l5) ^ sw));
        s16x8 kl1 = *(const s16x8*)(KL + rb + ((96 + 16 * l5) ^ sw));
        f32x16 a = ZERO16;
        a = __builtin_amdgcn_mfma_f32_32x32x16_bf16(ql0, kh0, a, 0, 0, 0);
        a = __builtin_amdgcn_mfma_f32_32x32x16_bf16(qh0, kl0, a, 0, 0, 0);
        a = __builtin_amdgcn_mfma_f32_32x32x16_bf16(qh0, kh0, a, 0, 0, 0);
        a = __builtin_amdgcn_mfma_f32_32x32x16_bf16(ql1, kh1, a, 0, 0, 0);
        a = __builtin_amdgcn_mfma_f32_32x32x16_bf16(qh1, kl1, a, 0, 0, 0);
        a = __builtin_amdgcn_mfma_f32_32x32x16_bf16(qh1, kh1, a, 0, 0, 0);
#pragma unroll
        for (int r = 0; r < 16; r++) {
            float nm = fmaxf(rmax[r], a[r]);
            rsum[r] = rsum[r] * __expf(rmax[r] - nm) + __expf(a[r] - nm);
            rmax[r] = nm;
        }
        __syncthreads();
    }

#pragma unroll
    for (int r = 0; r < 16; r++) {
#pragma unroll
        for (int off = 16; off >= 1; off >>= 1) {
            float om = __shfl_xor(rmax[r], off);
            float os = __shfl_xor(rsum[r], off);
            float nm = fmaxf(rmax[r], om);
            rsum[r] = rsum[r] * __expf(rmax[r] - nm) + os * __expf(om - nm);
            rmax[r] = nm;
        }
    }
    if (l31 == 0) {
#pragma unroll
        for (int r = 0; r < 16; r++) { Sm[w][l5][r] = rmax[r]; Ss[w][l5][r] = rsum[r]; }
    }
    __syncthreads();
    if (w < 2 && l31 == 0) {
#pragma unroll
        for (int r = 0; r < 16; r++) {
            float M = -1e30f;
#pragma unroll
            for (int j = 0; j < 4; j++) M = fmaxf(M, Sm[w + 2 * j][l5][r]);
            float S = 0.f;
#pragma unroll
            for (int j = 0; j < 4; j++)
                S += Ss[w + 2 * j][l5][r] * __expf(Sm[w + 2 * j][l5][r] - M);
            int m = mt * 64 + w * 32 + (r & 3) + 8 * (r >> 2) + 4 * l5;
            lse[b * NN + m] = M + __logf(S);
        }
    }
}

// ---------------------------------------------------------------- out -----
// 512 blocks: ch=bid&1 (c-half 128), b=(bid>>1)&3, mt=bid>>3 (64 m-tiles).
// 8 waves: energy wave=(strip,ns); PV wave=(strip,csub). All-LDS fragments.
__global__ __launch_bounds__(512, 4) void out_kernel(
    const u16* __restrict__ qhi, const u16* __restrict__ qlo,
    const u16* __restrict__ khi, const u16* __restrict__ klo,
    const u16* __restrict__ vbf, const float* __restrict__ lse,
    const float* __restrict__ x, const float* __restrict__ gamma,
    float* __restrict__ out)
{
    __shared__ u16 Klds[128 * 64];    // 16 KB [n][hi|lo]
    __shared__ u16 Vlds[128 * 128];   // 32 KB [c][n]
    __shared__ u16 Plds[64 * 128];    // 16 KB [m][n]
    int bid = blockIdx.x;
    int ch = bid & 1;
    int b  = (bid >> 1) & 3;
    int mt = bid >> 3;
    int tid = threadIdx.x;
    int w = tid >> 6, l = tid & 63;
    int l5 = l >> 5, l31 = l & 31;
    int strip = w & 1, ns = w >> 1, csub = w >> 1;
    int mS = mt * 64 + strip * 32;

    size_t qo = ((size_t)b * NN + mS + l31) * 32 + 8 * l5;
    s16x8 qh0 = *(const s16x8*)(qhi + qo), ql0 = *(const s16x8*)(qlo + qo);
    s16x8 qh1 = *(const s16x8*)(qhi + qo + 16), ql1 = *(const s16x8*)(qlo + qo + 16);

    float lr[16];
#pragma unroll
    for (int r = 0; r < 16; r++)
        lr[r] = lse[b * NN + mS + (r & 3) + 8 * (r >> 2) + 4 * l5];

    int sn = tid >> 2, sq = tid & 3;       // K staging
    int vc = tid >> 4, vk = tid & 15;      // V staging
    char* KL = (char*)Klds; char* VL = (char*)Vlds; char* PL = (char*)Plds;

    int nn = ns * 32 + l31;
    int krb = nn * 128, ksw = (nn & 7) << 4;
    int am = strip * 32 + l31;
    int arb = am * 256, asw = (am & 15) << 4;
    int cc = csub * 32 + l31;
    int vrb = cc * 256, vsw = (cc & 15) << 4;

    f32x16 acc = ZERO16;

    for (int it = 0; it < 32; it++) {
        int n0 = it * 128;
        // stage K (32 B/thread)
        {
            int swz = (sn & 7) << 4;
            *(s16x8*)(KL + sn * 128 + ((sq * 16) ^ swz)) =
                *(const s16x8*)((const char*)(khi + ((size_t)b * NN + n0 + sn) * 32) + sq * 16);
            *(s16x8*)(KL + sn * 128 + ((64 + sq * 16) ^ swz)) =
                *(const s16x8*)((const char*)(klo + ((size_t)b * NN + n0 + sn) * 32) + sq * 16);
        }
        // stage V (64 B/thread)
#pragma unroll
        for (int j = 0; j < 4; j++) {
            int c = vc + 32 * j;
            const u16* src = vbf + ((size_t)b * CC + ch * 128 + c) * NN + n0 + vk * 8;
            *(s16x8*)(VL + c * 256 + ((vk * 16) ^ ((c & 15) << 4))) = *(const s16x8*)src;
        }
        __syncthreads();
        // energy + P
        {
            s16x8 kh0 = *(const s16x8*)(KL + krb + ((16 * l5) ^ ksw));
            s16x8 kh1 = *(const s16x8*)(KL + krb + ((32 + 16 * l5) ^ ksw));
            s16x8 kl0 = *(const s16x8*)(KL + krb + ((64 + 16 * l5) ^ ksw));
            s16x8 kl1 = *(const s16x8*)(KL + krb + ((96 + 16 * l5) ^ ksw));
            f32x16 a = ZERO16;
            a = __builtin_amdgcn_mfma_f32_32x32x16_bf16(ql0, kh0, a, 0, 0, 0);
            a = __builtin_amdgcn_mfma_f32_32x32x16_bf16(qh0, kl0, a, 0, 0, 0);
            a = __builtin_amdgcn_mfma_f32_32x32x16_bf16(qh0, kh0, a, 0, 0, 0);
            a = __builtin_amdgcn_mfma_f32_32x32x16_bf16(ql1, kh1, a, 0, 0, 0);
            a = __builtin_amdgcn_mfma_f32_32x32x16_bf16(qh1, kl1, a, 0, 0, 0);
            a = __builtin_amdgcn_mfma_f32_32x32x16_bf16(qh1, kh1, a, 0, 0, 0);
#pragma unroll
            for (int r = 0; r < 16; r++) {
                float p = __expf(a[r] - lr[r]);
                int m = strip * 32 + (r & 3) + 8 * (r >> 2) + 4 * l5;
                *(u16*)(PL + m * 256 + ((nn * 2) ^ ((m & 15) << 4))) = f2bf(p);
            }
        }
        __syncthreads();
        // PV
#pragma unroll
        for (int ks = 0; ks < 8; ks++) {
            s16x8 pa = *(const s16x8*)(PL + arb + ((ks * 32 + 16 * l5) ^ asw));
            s16x8 vv = *(const s16x8*)(VL + vrb + ((ks * 32 + 16 * l5) ^ vsw));
            acc = __builtin_amdgcn_mfma_f32_32x32x16_bf16(pa, vv, acc, 0, 0, 0);
        }
        __syncthreads();
    }

    float gm = gamma[0];
    int c = ch * 128 + csub * 32 + l31;
#pragma unroll
    for (int t = 0; t < 4; t++) {
        size_t o = ((size_t)b * CC + c) * NN + mS + 8 * t + 4 * l5;
        float4 x4 = *(const float4*)(x + o);
        float4 r4;
        r4.x = fmaf(gm, acc[4 * t + 0], x4.x);
        r4.y = fmaf(gm, acc[4 * t + 1], x4.y);
        r4.z = fmaf(gm, acc[4 * t + 2], x4.z);
        r4.w = fmaf(gm, acc[4 * t + 3], x4.w);
        *(float4*)(out + o) = r4;
    }
}

// ---------------------------------------------------------------- launch --
extern "C" void kernel_launch(void* const* d_in, const int* in_sizes, int n_in,
                              void* d_out, int out_size, void* d_ws, size_t ws_size,
                              hipStream_t stream)
{
    const float* x     = (const float*)d_in[0];
    const float* g0    = (const float*)d_in[1];
    const float* Wq    = (const float*)d_in[2];
    const float* bq    = (const float*)d_in[3];
    const float* Wk    = (const float*)d_in[4];
    const float* bk    = (const float*)d_in[5];
    const float* Wv    = (const float*)d_in[6];
    const float* bv    = (const float*)d_in[7];
    const float* gamma = (const float*)d_in[8];
    float* out = (float*)d_out;

    char* p = (char*)d_ws;
    u16* qhi = (u16*)p; p += (size_t)4 * NN * 32 * 2;
    u16* qlo = (u16*)p; p += (size_t)4 * NN * 32 * 2;
    u16* khi = (u16*)p; p += (size_t)4 * NN * 32 * 2;
    u16* klo = (u16*)p; p += (size_t)4 * NN * 32 * 2;
    u16* vbf = (u16*)p; p += (size_t)4 * CC * NN * 2;
    float* gate = (float*)p; p += (size_t)4 * NN * 4;
    float* lse  = (float*)p; p += (size_t)4 * NN * 4;

    hipLaunchKernelGGL(gate_kernel, dim3(64), dim3(256), 0, stream, g0, gate);
    hipLaunchKernelGGL(qkv_kernel, dim3(512), dim3(256), 0, stream,
                       x, Wq, bq, Wk, bk, Wv, bv, gate, qhi, qlo, khi, klo, vbf);
    hipLaunchKernelGGL(stats_kernel, dim3(256), dim3(512), 0, stream,
                       qhi, qlo, khi, klo, lse);
    hipLaunchKernelGGL(out_kernel, dim3(512), dim3(512), 0, stream,
                       qhi, qlo, khi, klo, vbf, lse, x, gamma, out);
}

// Round 5
// 137.134 us; speedup vs baseline: 7.4380x; 1.3523x over previous
//
#include <hip/hip_runtime.h>
#include <math.h>

#define NN 4096
#define CC 256

typedef unsigned short u16;
typedef float f32x16 __attribute__((ext_vector_type(16)));
typedef short s16x8 __attribute__((ext_vector_type(8)));

#define ZERO16 {0.f,0.f,0.f,0.f,0.f,0.f,0.f,0.f,0.f,0.f,0.f,0.f,0.f,0.f,0.f,0.f}

#define GLOAD_LDS16(gsrc, ldst) \
    __builtin_amdgcn_global_load_lds((const __attribute__((address_space(1))) unsigned int*)(gsrc), \
                                     (__attribute__((address_space(3))) unsigned int*)(ldst), 16, 0, 0)

__device__ __forceinline__ u16 f2bf(float f){
    unsigned u = __float_as_uint(f);
    return (u16)((u + 0x7fffu + ((u >> 16) & 1u)) >> 16);
}
__device__ __forceinline__ float bf2f(u16 h){
    return __uint_as_float(((unsigned)h) << 16);
}

// ---------------------------------------------------------------- gate + W prep
__global__ __launch_bounds__(256) void gate_kernel(
    const float* __restrict__ g0, const float* __restrict__ Wq,
    const float* __restrict__ Wk, const float* __restrict__ Wv,
    float* __restrict__ gate,
    u16* __restrict__ wqhi, u16* __restrict__ wqlo,
    u16* __restrict__ wkhi, u16* __restrict__ wklo,
    u16* __restrict__ wvbf)
{
    int idx = blockIdx.x * 256 + threadIdx.x;      // 0..16383
    int b  = idx >> 12;
    int hw = idx & 4095;
    int h = hw >> 6, w = hw & 63;
    float ys = h * (31.0f / 63.0f);
    float xs = w * (31.0f / 63.0f);
    int y0 = (int)ys, x0 = (int)xs;
    int y1 = min(y0 + 1, 31), x1 = min(x0 + 1, 31);
    float wy = ys - (float)y0, wx = xs - (float)x0;
    const float* g = g0 + b * 1024;
    float g00 = g[y0 * 32 + x0], g01 = g[y0 * 32 + x1];
    float g10 = g[y1 * 32 + x0], g11 = g[y1 * 32 + x1];
    float top = g00 * (1.0f - wx) + g01 * wx;
    float bot = g10 * (1.0f - wx) + g11 * wx;
    float val = top * (1.0f - wy) + bot * wy;
    gate[idx] = 1.0f + 1.0f / (1.0f + __expf(-val));

    if (idx < 8192) {
        float a = Wq[idx];
        u16 ha = f2bf(a);
        wqhi[idx] = ha; wqlo[idx] = f2bf(a - bf2f(ha));
        float c = Wk[idx];
        u16 hc = f2bf(c);
        wkhi[idx] = hc; wklo[idx] = f2bf(c - bf2f(hc));
    }
#pragma unroll
    for (int j = 0; j < 4; j++)
        wvbf[idx + j * 16384] = f2bf(Wv[idx + j * 16384]);
}

// ---------------------------------------------------------------- qkv -----
// 256 blocks (b, nt of 64 n). x staged once in LDS as bf16 hi/lo [n][c] swizzled.
// 8 waves: 0..3 = q/k (proj, nhalf) hi/lo-split MFMA; 4..7 = v (64 c each).
__global__ __launch_bounds__(512, 4) void qkv_kernel(
    const float* __restrict__ x,
    const u16* __restrict__ wqhi, const u16* __restrict__ wqlo,
    const u16* __restrict__ wkhi, const u16* __restrict__ wklo,
    const u16* __restrict__ wvbf,
    const float* __restrict__ bq, const float* __restrict__ bk,
    const float* __restrict__ bv, const float* __restrict__ gate,
    u16* __restrict__ qhi, u16* __restrict__ qlo,
    u16* __restrict__ khi, u16* __restrict__ klo,
    u16* __restrict__ vbf)
{
    __shared__ u16 Xh[64 * 256];   // [n][c] swizzled, 32 KB
    __shared__ u16 Xl[64 * 256];   // 32 KB
    int bid = blockIdx.x;
    int b  = (bid >> 1) & 3;
    int nt = (bid >> 3) | ((bid & 1) << 5);
    int n0 = nt * 64;
    int tid = threadIdx.x;

    // ---- stage x -> LDS (hi/lo bf16, [n][c], XOR-swizzled rows)
    {
        const float* xb = x + (size_t)b * CC * NN;
        int cb = tid >> 4;          // 0..31
        int nc = tid & 15;          // 4-n chunk
#pragma unroll
        for (int j = 0; j < 8; j++) {
            int c = cb + 32 * j;
            float4 xv = *(const float4*)(xb + (size_t)c * NN + n0 + nc * 4);
            float xf[4] = {xv.x, xv.y, xv.z, xv.w};
#pragma unroll
            for (int i = 0; i < 4; i++) {
                int n = nc * 4 + i;
                u16 hv = f2bf(xf[i]);
                u16 lv = f2bf(xf[i] - bf2f(hv));
                int u = n * 256 + (c ^ ((n & 31) << 3));
                Xh[u] = hv; Xl[u] = lv;
            }
        }
    }
    __syncthreads();

    int w = tid >> 6, l = tid & 63;
    int l5 = l >> 5, l31 = l & 31;

    if (w < 4) {
        // ---- q,k
        int proj = w & 1, nh = w >> 1;
        const u16* Whi = proj ? wkhi : wqhi;
        const u16* Wlo = proj ? wklo : wqlo;
        const float* bias = proj ? bk : bq;
        u16* dhi = proj ? khi : qhi;
        u16* dlo = proj ? klo : qlo;
        int nl = nh * 32 + l31;
        int swz = (nl & 31) << 3;

        f32x16 acc = ZERO16;
        for (int ks = 0; ks < 16; ks++) {
            int c0 = ks * 16 + 8 * l5;
            s16x8 whi = *(const s16x8*)(Whi + l31 * 256 + c0);
            s16x8 wlo = *(const s16x8*)(Wlo + l31 * 256 + c0);
            int u = nl * 256 + (c0 ^ swz);
            s16x8 xh = *(const s16x8*)(Xh + u);
            s16x8 xl = *(const s16x8*)(Xl + u);
            acc = __builtin_amdgcn_mfma_f32_32x32x16_bf16(whi, xh, acc, 0, 0, 0);
            acc = __builtin_amdgcn_mfma_f32_32x32x16_bf16(whi, xl, acc, 0, 0, 0);
            acc = __builtin_amdgcn_mfma_f32_32x32x16_bf16(wlo, xh, acc, 0, 0, 0);
        }
        int n = n0 + nl;
        float g = gate[b * NN + n];
        size_t rowo = ((size_t)b * NN + n) * 32;
#pragma unroll
        for (int t = 0; t < 4; t++) {
            int ob = 8 * t + 4 * l5;
            unsigned h01 = 0, h23 = 0, l01 = 0, l23 = 0;
#pragma unroll
            for (int j = 0; j < 4; j++) {
                float v = (acc[4 * t + j] + bias[ob + j]) * g;
                u16 h = f2bf(v);
                u16 lo = f2bf(v - bf2f(h));
                if (j < 2) { h01 |= ((unsigned)h) << (16 * j); l01 |= ((unsigned)lo) << (16 * j); }
                else       { h23 |= ((unsigned)h) << (16 * (j - 2)); l23 |= ((unsigned)lo) << (16 * (j - 2)); }
            }
            *(unsigned*)(dhi + rowo + ob)     = h01;
            *(unsigned*)(dhi + rowo + ob + 2) = h23;
            *(unsigned*)(dlo + rowo + ob)     = l01;
            *(unsigned*)(dlo + rowo + ob + 2) = l23;
        }
    } else {
        // ---- v: wave covers 64 c x 64 n
        int vw = w - 4;
        int cB = vw * 64;
        int swz = (l31 & 31) << 3;
        f32x16 acc[2][2] = {{ZERO16, ZERO16}, {ZERO16, ZERO16}};
        for (int ks = 0; ks < 16; ks++) {
            int c0 = ks * 16 + 8 * l5;
            int u0 = l31 * 256 + (c0 ^ swz);
            s16x8 xh0 = *(const s16x8*)(Xh + u0);
            s16x8 xh1 = *(const s16x8*)(Xh + u0 + 32 * 256);
#pragma unroll
            for (int ct = 0; ct < 2; ct++) {
                s16x8 wv = *(const s16x8*)(wvbf + (size_t)(cB + ct * 32 + l31) * 256 + c0);
                acc[ct][0] = __builtin_amdgcn_mfma_f32_32x32x16_bf16(wv, xh0, acc[ct][0], 0, 0, 0);
                acc[ct][1] = __builtin_amdgcn_mfma_f32_32x32x16_bf16(wv, xh1, acc[ct][1], 0, 0, 0);
            }
        }
#pragma unroll
        for (int nh2 = 0; nh2 < 2; nh2++) {
            int n = n0 + nh2 * 32 + l31;
            float g = gate[b * NN + n];
#pragma unroll
            for (int ct = 0; ct < 2; ct++) {
#pragma unroll
                for (int r = 0; r < 16; r++) {
                    int c = cB + ct * 32 + (r & 3) + 8 * (r >> 2) + 4 * l5;
                    vbf[((size_t)b * CC + c) * NN + n] = f2bf((acc[ct][nh2][r] + bv[c]) * g);
                }
            }
        }
    }
}

// ---------------------------------------------------------------- stats ---
// 256 blocks x 8 waves (strip, ns). K direct from global, no in-loop barriers.
__global__ __launch_bounds__(512, 4) void stats_kernel(
    const u16* __restrict__ qhi, const u16* __restrict__ qlo,
    const u16* __restrict__ khi, const u16* __restrict__ klo,
    float* __restrict__ lse)
{
    __shared__ float Sm[8][2][16], Ss[8][2][16];
    int bid = blockIdx.x;
    int b  = (bid >> 1) & 3;
    int mt = (bid >> 3) | ((bid & 1) << 5);
    int tid = threadIdx.x;
    int w = tid >> 6, l = tid & 63;
    int l5 = l >> 5, l31 = l & 31;
    int strip = w & 1, ns = w >> 1;
    int mS = mt * 64 + strip * 32;

    size_t qo = ((size_t)b * NN + mS + l31) * 32 + 8 * l5;
    s16x8 qh0 = *(const s16x8*)(qhi + qo), ql0 = *(const s16x8*)(qlo + qo);
    s16x8 qh1 = *(const s16x8*)(qhi + qo + 16), ql1 = *(const s16x8*)(qlo + qo + 16);

    float rmax[16], rsum[16];
#pragma unroll
    for (int r = 0; r < 16; r++) { rmax[r] = -1e30f; rsum[r] = 0.f; }

    for (int it = 0; it < 32; it++) {
        size_t ko = ((size_t)b * NN + it * 128 + ns * 32 + l31) * 32 + 8 * l5;
        s16x8 kh0 = *(const s16x8*)(khi + ko), kl0 = *(const s16x8*)(klo + ko);
        s16x8 kh1 = *(const s16x8*)(khi + ko + 16), kl1 = *(const s16x8*)(klo + ko + 16);
        f32x16 a = ZERO16;
        a = __builtin_amdgcn_mfma_f32_32x32x16_bf16(ql0, kh0, a, 0, 0, 0);
        a = __builtin_amdgcn_mfma_f32_32x32x16_bf16(qh0, kl0, a, 0, 0, 0);
        a = __builtin_amdgcn_mfma_f32_32x32x16_bf16(qh0, kh0, a, 0, 0, 0);
        a = __builtin_amdgcn_mfma_f32_32x32x16_bf16(ql1, kh1, a, 0, 0, 0);
        a = __builtin_amdgcn_mfma_f32_32x32x16_bf16(qh1, kl1, a, 0, 0, 0);
        a = __builtin_amdgcn_mfma_f32_32x32x16_bf16(qh1, kh1, a, 0, 0, 0);
#pragma unroll
        for (int r = 0; r < 16; r++) {
            float nm = fmaxf(rmax[r], a[r]);
            rsum[r] = rsum[r] * __expf(rmax[r] - nm) + __expf(a[r] - nm);
            rmax[r] = nm;
        }
    }

#pragma unroll
    for (int r = 0; r < 16; r++) {
#pragma unroll
        for (int off = 16; off >= 1; off >>= 1) {
            float om = __shfl_xor(rmax[r], off);
            float os = __shfl_xor(rsum[r], off);
            float nm = fmaxf(rmax[r], om);
            rsum[r] = rsum[r] * __expf(rmax[r] - nm) + os * __expf(om - nm);
            rmax[r] = nm;
        }
    }
    if (l31 == 0) {
#pragma unroll
        for (int r = 0; r < 16; r++) { Sm[w][l5][r] = rmax[r]; Ss[w][l5][r] = rsum[r]; }
    }
    __syncthreads();
    if (w < 2 && l31 == 0) {
#pragma unroll
        for (int r = 0; r < 16; r++) {
            float M = -1e30f;
#pragma unroll
            for (int j = 0; j < 4; j++) M = fmaxf(M, Sm[w + 2 * j][l5][r]);
            float S = 0.f;
#pragma unroll
            for (int j = 0; j < 4; j++)
                S += Ss[w + 2 * j][l5][r] * __expf(Sm[w + 2 * j][l5][r] - M);
            int m = mt * 64 + w * 32 + (r & 3) + 8 * (r >> 2) + 4 * l5;
            lse[b * NN + m] = M + __logf(S);
        }
    }
}

// ---------------------------------------------------------------- out -----
// 256 blocks (b, mt): 64 m x 256 c, n-tile 128. 8 waves = (strip=w&1, cq=w>>1):
//   energy role: S-tile (m strip*32, n cq*32), K direct global.
//   PV role:     OWNS output block m=strip*32(32) x c=cq*64(64); sums ALL 128 n.
// V staged by global_load_lds with pre-inverse-swizzled per-lane source.
__global__ __launch_bounds__(512, 2) void out_kernel(
    const u16* __restrict__ qhi, const u16* __restrict__ qlo,
    const u16* __restrict__ khi, const u16* __restrict__ klo,
    const u16* __restrict__ vbf, const float* __restrict__ lse,
    const float* __restrict__ x, const float* __restrict__ gamma,
    float* __restrict__ out)
{
    __shared__ u16 Vl[256 * 128];   // [c][n] swizzled, 64 KB
    __shared__ u16 Pl[64 * 128];    // [m][n] swizzled, 16 KB
    int bid = blockIdx.x;
    int b  = (bid >> 1) & 3;
    int mt = (bid >> 3) | ((bid & 1) << 5);
    int tid = threadIdx.x;
    int w = tid >> 6, l = tid & 63;
    int l5 = l >> 5, l31 = l & 31;
    int strip = w & 1, cq = w >> 1;
    int mS = mt * 64 + strip * 32;

    size_t qo = ((size_t)b * NN + mS + l31) * 32 + 8 * l5;
    s16x8 qh0 = *(const s16x8*)(qhi + qo), ql0 = *(const s16x8*)(qlo + qo);
    s16x8 qh1 = *(const s16x8*)(qhi + qo + 16), ql1 = *(const s16x8*)(qlo + qo + 16);

    float lr[16];
#pragma unroll
    for (int r = 0; r < 16; r++)
        lr[r] = lse[b * NN + mS + (r & 3) + 8 * (r >> 2) + 4 * l5];

    f32x16 acc[2] = {ZERO16, ZERO16};
    const u16* vb = vbf + (size_t)b * CC * NN;

    for (int it = 0; it < 32; it++) {
        int n0 = it * 128;
        // ---- stage V (async DMA, inverse-swizzled per-lane source)
#pragma unroll
        for (int j = 0; j < 8; j++) {
            int s = w * 512 + j * 64 + l;
            int c = s >> 4, chk = s & 15;
            const u16* src = vb + (size_t)c * NN + n0 + ((chk * 8) ^ ((c & 15) << 3));
            GLOAD_LDS16(src, Vl + (size_t)(w * 512 + j * 64) * 8);
        }
        // ---- energy: S-tile (strip, nsub=cq), K direct from global
        {
            size_t ko = ((size_t)b * NN + n0 + cq * 32 + l31) * 32 + 8 * l5;
            s16x8 kh0 = *(const s16x8*)(khi + ko), kl0 = *(const s16x8*)(klo + ko);
            s16x8 kh1 = *(const s16x8*)(khi + ko + 16), kl1 = *(const s16x8*)(klo + ko + 16);
            f32x16 a = ZERO16;
            a = __builtin_amdgcn_mfma_f32_32x32x16_bf16(ql0, kh0, a, 0, 0, 0);
            a = __builtin_amdgcn_mfma_f32_32x32x16_bf16(qh0, kl0, a, 0, 0, 0);
            a = __builtin_amdgcn_mfma_f32_32x32x16_bf16(qh0, kh0, a, 0, 0, 0);
            a = __builtin_amdgcn_mfma_f32_32x32x16_bf16(ql1, kh1, a, 0, 0, 0);
            a = __builtin_amdgcn_mfma_f32_32x32x16_bf16(qh1, kl1, a, 0, 0, 0);
            a = __builtin_amdgcn_mfma_f32_32x32x16_bf16(qh1, kh1, a, 0, 0, 0);
#pragma unroll
            for (int r = 0; r < 16; r++) {
                float p = __expf(a[r] - lr[r]);
                int m = strip * 32 + (r & 3) + 8 * (r >> 2) + 4 * l5;
                int nc = cq * 32 + l31;
                Pl[m * 128 + (nc ^ ((m & 15) << 3))] = f2bf(p);
            }
        }
        __syncthreads();
        // ---- PV: wave owns (m strip*32..+32) x (c cq*64..+64), all 128 n
#pragma unroll
        for (int ks = 0; ks < 8; ks++) {
            int col = ks * 16 + 8 * l5;
            int mr = strip * 32 + l31;
            s16x8 pa = *(const s16x8*)(Pl + mr * 128 + (col ^ ((mr & 15) << 3)));
            int c0r = cq * 64 + l31, c1r = cq * 64 + 32 + l31;
            s16x8 vv0 = *(const s16x8*)(Vl + c0r * 128 + (col ^ ((c0r & 15) << 3)));
            s16x8 vv1 = *(const s16x8*)(Vl + c1r * 128 + (col ^ ((c1r & 15) << 3)));
            acc[0] = __builtin_amdgcn_mfma_f32_32x32x16_bf16(pa, vv0, acc[0], 0, 0, 0);
            acc[1] = __builtin_amdgcn_mfma_f32_32x32x16_bf16(pa, vv1, acc[1], 0, 0, 0);
        }
        __syncthreads();
    }

    float gm = gamma[0];
#pragma unroll
    for (int cs = 0; cs < 2; cs++) {
        int c = cq * 64 + cs * 32 + l31;
#pragma unroll
        for (int t = 0; t < 4; t++) {
            size_t o = ((size_t)b * CC + c) * NN + mS + 8 * t + 4 * l5;
            float4 x4 = *(const float4*)(x + o);
            float4 r4;
            r4.x = fmaf(gm, acc[cs][4 * t + 0], x4.x);
            r4.y = fmaf(gm, acc[cs][4 * t + 1], x4.y);
            r4.z = fmaf(gm, acc[cs][4 * t + 2], x4.z);
            r4.w = fmaf(gm, acc[cs][4 * t + 3], x4.w);
            *(float4*)(out + o) = r4;
        }
    }
}

// ---------------------------------------------------------------- launch --
extern "C" void kernel_launch(void* const* d_in, const int* in_sizes, int n_in,
                              void* d_out, int out_size, void* d_ws, size_t ws_size,
                              hipStream_t stream)
{
    const float* x     = (const float*)d_in[0];
    const float* g0    = (const float*)d_in[1];
    const float* Wq    = (const float*)d_in[2];
    const float* bq    = (const float*)d_in[3];
    const float* Wk    = (const float*)d_in[4];
    const float* bk    = (const float*)d_in[5];
    const float* Wv    = (const float*)d_in[6];
    const float* bv    = (const float*)d_in[7];
    const float* gamma = (const float*)d_in[8];
    float* out = (float*)d_out;

    char* p = (char*)d_ws;
    u16* qhi = (u16*)p; p += (size_t)4 * NN * 32 * 2;
    u16* qlo = (u16*)p; p += (size_t)4 * NN * 32 * 2;
    u16* khi = (u16*)p; p += (size_t)4 * NN * 32 * 2;
    u16* klo = (u16*)p; p += (size_t)4 * NN * 32 * 2;
    u16* vbf = (u16*)p; p += (size_t)4 * CC * NN * 2;
    float* gate = (float*)p; p += (size_t)4 * NN * 4;
    float* lse  = (float*)p; p += (size_t)4 * NN * 4;
    u16* wqhi = (u16*)p; p += 8192 * 2;
    u16* wqlo = (u16*)p; p += 8192 * 2;
    u16* wkhi = (u16*)p; p += 8192 * 2;
    u16* wklo = (u16*)p; p += 8192 * 2;
    u16* wvbf = (u16*)p; p += 65536 * 2;

    hipLaunchKernelGGL(gate_kernel, dim3(64), dim3(256), 0, stream,
                       g0, Wq, Wk, Wv, gate, wqhi, wqlo, wkhi, wklo, wvbf);
    hipLaunchKernelGGL(qkv_kernel, dim3(256), dim3(512), 0, stream,
                       x, wqhi, wqlo, wkhi, wklo, wvbf, bq, bk, bv, gate,
                       qhi, qlo, khi, klo, vbf);
    hipLaunchKernelGGL(stats_kernel, dim3(256), dim3(512), 0, stream,
                       qhi, qlo, khi, klo, lse);
    hipLaunchKernelGGL(out_kernel, dim3(256), dim3(512), 0, stream,
                       qhi, qlo, khi, klo, vbf, lse, x, gamma, out);
}